// Round 22
// baseline (214.910 us; speedup 1.0000x reference)
//
#include <hip/hip_runtime.h>
#include <hip/hip_cooperative_groups.h>

namespace cg = cooperative_groups;

#define N 8192

// Smooth part: binned autocorrelation of F = H8 (8 non-min images) + g_cap(r_min).
#define BGRID 64
#define BINV 6.4f
#define NBINS (BGRID * BGRID)      // 4096
#define FDIM 127
#define FSIZE (FDIM * FDIM)        // 16129
#define FH 0.15625f                // 10/64

// poly(s) = GA + GB*s + GC*s^2 (s = r^2), C1-matched to 1/r at rc=0.5.
#define RC2 0.25f
#define GA 3.75f
#define GB (-10.0f)
#define GC 12.0f

// Per-slice privatized cell grid for the short-range residual (r < 0.5 only).
#define CELLG 20
#define CELLINV 2.0f
#define NCELLS (CELLG * CELLG)     // 400
#define NSLICE 8
#define CAPS 24
#define SRCAP 384

// Cooperative grid roles.
#define NBLK 912                   // 128 F | 4 hist | 8 KE | 8 build; then 512 corr + 400 sr
#define NCORR 512

// ws layout (float-index offsets)
#define WS_F 0                     // 16384
#define WS_HIST 16384              // 4096 bins x 4 slices (u32, interleaved) -> 16384 u32
#define WS_CNT 32768               // 400*8 u32 (pad 4096)
#define WS_CELLS 36864             // 400*8*24 float2 = 153600 floats
#define WS_CORR 190464             // 512
#define WS_SR 190976               // 512
#define WS_KE 191488               // 8

#define RSQ __builtin_amdgcn_rsqf

__global__ __launch_bounds__(128) void uber_kernel(const float* __restrict__ xy,
                                                   const float* __restrict__ pxy,
                                                   float* __restrict__ F,
                                                   unsigned* __restrict__ histI,
                                                   float* __restrict__ ke_part,
                                                   unsigned* __restrict__ cnt_g,
                                                   float2* __restrict__ cells,
                                                   float* __restrict__ corr_part,
                                                   float* __restrict__ sr_part,
                                                   float* __restrict__ out) {
    cg::grid_group grid = cg::this_grid();
    const int t = threadIdx.x;
    const int b = blockIdx.x;
    __shared__ unsigned smem_u[4096];          // 16 KB arena, aliased per role
    __shared__ float wsum[2];
    float* smem = (float*)smem_u;

    // ================= Phase A: build F, hist, KE, cells =================
    if (b < 128) {
        int k = b * 128 + t;
        if (k < FSIZE) {
            float a  = (float)(k % FDIM - 63) * FH;
            float bb = (float)(k / FDIM - 63) * FH;
            int ixm = (__builtin_fabsf(a)  <= 5.0f) ? 0 : (a  > 0.0f ? -1 : 1);
            int iym = (__builtin_fabsf(bb) <= 5.0f) ? 0 : (bb > 0.0f ? -1 : 1);
            float s = 0.0f;
            for (int iy = -1; iy <= 1; ++iy)
                for (int ix = -1; ix <= 1; ++ix) {
                    if (ix == ixm && iy == iym) continue;
                    float xs = __builtin_fmaf(10.0f, (float)ix, a);
                    float ys = __builtin_fmaf(10.0f, (float)iy, bb);
                    s += RSQ(xs * xs + ys * ys);
                }
            float ux = 5.0f - __builtin_fabsf(__builtin_fabsf(a) - 5.0f);
            float uy = 5.0f - __builtin_fabsf(__builtin_fabsf(bb) - 5.0f);
            float r2 = __builtin_fmaf(uy, uy, ux * ux);
            float gcap = (r2 >= RC2)
                       ? RSQ(r2)
                       : __builtin_fmaf(__builtin_fmaf(GC, r2, GB), r2, GA);
            F[k] = s + gcap;
        }
    } else if (b < 132) {
        // hist slice hb: 2048 points -> LDS histogram -> interleaved store
        unsigned* lh = smem_u;
        const int hb = b - 128;
        for (int k = t; k < NBINS; k += 128) lh[k] = 0u;
        __syncthreads();
        const float2* p2 = (const float2*)xy;
        for (int r = 0; r < 16; ++r) {
            float2 p = p2[hb * 2048 + r * 128 + t];
            int cx = (int)(p.x * BINV); cx = cx > 63 ? 63 : cx;
            int cy = (int)(p.y * BINV); cy = cy > 63 ? 63 : cy;
            atomicAdd(&lh[cy * BGRID + cx], 1u);
        }
        __syncthreads();
        for (int k = t; k < NBINS; k += 128) histI[k * 4 + hb] = lh[k];
    } else if (b < 140) {
        const int kb = b - 132;
        const float4* p4 = (const float4*)pxy;
        float acc = 0.0f;
        for (int k = kb * 512 + t; k < kb * 512 + 512; k += 128) {
            float4 v = p4[k];
            acc += 0.5f * (v.x * v.x + v.y * v.y + v.z * v.z + v.w * v.w);
        }
        for (int off = 32; off > 0; off >>= 1)
            acc += __shfl_down(acc, off, 64);
        if ((t & 63) == 0) wsum[t >> 6] = acc;
        __syncthreads();
        if (t == 0) ke_part[kb] = wsum[0] + wsum[1];
    } else if (b < 148) {
        // per-slice cell build: LDS cursors, plain global stores
        unsigned* cur = smem_u;
        const int pb = b - 140;
        const float2* p2 = (const float2*)xy;
        for (int k = t; k < NCELLS; k += 128) cur[k] = 0u;
        __syncthreads();
        for (int r = 0; r < 8; ++r) {
            float2 p = p2[pb * 1024 + r * 128 + t];
            int cx = (int)(p.x * CELLINV); cx = cx > CELLG - 1 ? CELLG - 1 : cx;
            int cy = (int)(p.y * CELLINV); cy = cy > CELLG - 1 ? CELLG - 1 : cy;
            int c = cy * CELLG + cx;
            unsigned slot = atomicAdd(&cur[c], 1u);
            if (slot < CAPS) cells[(c * NSLICE + pb) * CAPS + slot] = p;
        }
        __syncthreads();
        for (int k = t; k < NCELLS; k += 128) cnt_g[k * NSLICE + pb] = cur[k];
    }

    grid.sync();

    // ================= Phase B: corr (b<512) / short-range (512<=b<912) ==========
    if (b < NCORR) {
        float (*corrF)[128] = (float (*)[128])smem;           // 1024 floats
        float (*corrN)[64]  = (float (*)[64])(smem + 1024);   // 512 floats
        const uint4* h4 = (const uint4*)histI;
        const int y1 = b >> 3;
        const int y2b = (b & 7) * 8;
        const int x1 = t & 63;
        const int x2c = t >> 6;
        const int x2base = x2c * 32;
#pragma unroll
        for (int s = 0; s < 8; ++s) {
            if (t < FDIM)
                corrF[s][t] = F[(y1 - (y2b + s) + 63) * FDIM + t];
            if (t < 64) {
                uint4 v = h4[(y2b + s) * BGRID + t];
                corrN[s][t] = (float)(v.x + v.y + v.z + v.w);
            }
        }
        uint4 v1 = h4[y1 * BGRID + x1];
        float n1 = (float)(v1.x + v1.y + v1.z + v1.w);
        __syncthreads();
        const int fb = 63 + x1 - x2base;
        float acc = 0.0f;
#pragma unroll
        for (int s = 0; s < 8; ++s) {
            const float* Fr = &corrF[s][0];
            const float* Nr = &corrN[s][x2base];
            float sum = 0.0f;
#pragma unroll 8
            for (int k = 0; k < 32; ++k)
                sum = __builtin_fmaf(Nr[k], Fr[fb - k], sum);
            acc += sum;
        }
        acc *= n1;
        for (int off = 32; off > 0; off >>= 1)
            acc += __shfl_down(acc, off, 64);
        if ((t & 63) == 0) wsum[t >> 6] = acc;
        __syncthreads();
        if (t == 0) corr_part[b] = wsum[0] + wsum[1];
    } else {
        float* spx       = smem;                     // 384
        float* spy       = smem + 384;               // 384
        int*   stag      = (int*)(smem + 768);       // 384
        int*   segbase   = (int*)(smem + 1152);      // 73
        unsigned* seglen = (unsigned*)(smem + 1225); // 72
        int*   cc9       = (int*)(smem + 1297);      // 9

        const int c  = b - NCORR;                    // 0..399
        const int cx = c % CELLG, cy = c / CELLG;

        if (t < 9) {
            const int ox[9] = {0,-1,0,1,-1,1,-1,0,1};
            const int oy[9] = {0,-1,-1,-1,0,0,1,1,1};   // own cell first
            int cx2 = cx + ox[t];
            cx2 += (cx2 < 0) ? CELLG : 0;  cx2 -= (cx2 >= CELLG) ? CELLG : 0;
            int cy2 = cy + oy[t];
            cy2 += (cy2 < 0) ? CELLG : 0;  cy2 -= (cy2 >= CELLG) ? CELLG : 0;
            cc9[t] = cy2 * CELLG + cx2;
        }
        __syncthreads();
        if (t < 72) {
            unsigned L = cnt_g[cc9[t >> 3] * NSLICE + (t & 7)];
            seglen[t] = L > CAPS ? CAPS : L;
        }
        __syncthreads();
        if (t < 73) {
            int b2 = 0;
            for (int j = 0; j < t; ++j) b2 += (int)seglen[j];
            segbase[t] = b2;
        }
        __syncthreads();
        const int n0 = segbase[8];
        int M = segbase[72];  M = M > SRCAP ? SRCAP : M;

        for (int g = t; g < M; g += 128) {
            int lo = 0, hi = 71;
            while (lo < hi) {
                int mid = (lo + hi + 1) >> 1;
                if (segbase[mid] <= g) lo = mid; else hi = mid - 1;
            }
            int src = (cc9[lo >> 3] * NSLICE + (lo & 7)) * CAPS + (g - segbase[lo]);
            float2 q = cells[src];
            spx[g] = q.x;  spy[g] = q.y;  stag[g] = src;
        }
        __syncthreads();

        float acc = 0.0f;
        for (int i = 0; i < n0; ++i) {
            float pxi = spx[i], pyi = spy[i];
            int itag = stag[i];
            for (int j = t; j < M; j += 128) {
                float dx = pxi - spx[j];
                float dy = pyi - spy[j];
                float ux = 5.0f - __builtin_fabsf(__builtin_fabsf(dx) - 5.0f);
                float uy = 5.0f - __builtin_fabsf(__builtin_fabsf(dy) - 5.0f);
                float s2 = __builtin_fmaf(uy, uy, ux * ux);
                float v = RSQ(s2) - __builtin_fmaf(__builtin_fmaf(GC, s2, GB), s2, GA);
                bool ok = (s2 < RC2) && (stag[j] != itag);
                acc += ok ? v : 0.0f;
            }
        }
        for (int off = 32; off > 0; off >>= 1)
            acc += __shfl_down(acc, off, 64);
        if ((t & 63) == 0) wsum[t >> 6] = acc;
        __syncthreads();
        if (t == 0) sr_part[c] = wsum[0] + wsum[1];
    }

    grid.sync();

    // ================= Phase C: final reduction (block 0) =================
    if (b == 0) {
        float acc = 0.0f;
        for (int k = t; k < NCORR; k += 128) acc += corr_part[k];
        for (int k = t; k < NCELLS; k += 128) acc += sr_part[k];
        if (t < 8) acc += ke_part[t];
        if (t == 0) acc -= (float)N * F[63 * FDIM + 63];   // remove i==j bin pairs
        for (int off = 32; off > 0; off >>= 1)
            acc += __shfl_down(acc, off, 64);
        if ((t & 63) == 0) wsum[t >> 6] = acc;
        __syncthreads();
        if (t == 0) out[0] = wsum[0] + wsum[1];
    }
}

extern "C" void kernel_launch(void* const* d_in, const int* in_sizes, int n_in,
                              void* d_out, int out_size, void* d_ws, size_t ws_size,
                              hipStream_t stream) {
    const float* xy  = (const float*)d_in[0];
    const float* pxy = (const float*)d_in[1];
    float* out       = (float*)d_out;
    float* wsf       = (float*)d_ws;
    float* F         = wsf + WS_F;
    unsigned* histI  = (unsigned*)(wsf + WS_HIST);
    unsigned* cnt_g  = (unsigned*)(wsf + WS_CNT);
    float2* cells    = (float2*)(wsf + WS_CELLS);
    float* corr_part = wsf + WS_CORR;
    float* sr_part   = wsf + WS_SR;
    float* ke_part   = wsf + WS_KE;

    void* args[] = {(void*)&xy, (void*)&pxy, (void*)&F, (void*)&histI, (void*)&ke_part,
                    (void*)&cnt_g, (void*)&cells, (void*)&corr_part, (void*)&sr_part,
                    (void*)&out};
    hipLaunchCooperativeKernel((const void*)uber_kernel, dim3(NBLK), dim3(128),
                               args, 0, stream);
}

// Round 23
// 35.181 us; speedup vs baseline: 6.1087x; 6.1087x over previous
//
#include <hip/hip_runtime.h>

#define N 8192

// Smooth part: binned autocorrelation of F = H8 (8 non-min images) + g_cap(r_min).
#define BGRID 64
#define BINV 6.4f
#define NBINS (BGRID * BGRID)      // 4096
#define FDIM 127
#define FH 0.15625f                // 10/64

// poly(s) = GA + GB*s + GC*s^2 (s = r^2), C1-matched to 1/r at rc=0.5.
#define RC2 0.25f
#define GA 3.75f
#define GB (-10.0f)
#define GC 12.0f

// Cell geometry for the short-range residual (r < 0.5 only).
#define CELLG 20
#define CELLINV 2.0f
#define NCELLS (CELLG * CELLG)     // 400
#define SRCAP 384                  // 3x3 neighborhood capacity (avg 185)

#define NCORR 512
#define NBLK (NCORR + NCELLS)      // 912

// ws layout (float-index offsets)
#define WS_CORR 0                  // 512
#define WS_SR 512                  // 512

#define RSQ __builtin_amdgcn_rsqf

// F node: H8 (8 non-min images) + g_cap(min image), same ops as the verified build.
__device__ __forceinline__ float Fnode(float a, float bb) {
    int ixm = (__builtin_fabsf(a)  <= 5.0f) ? 0 : (a  > 0.0f ? -1 : 1);
    int iym = (__builtin_fabsf(bb) <= 5.0f) ? 0 : (bb > 0.0f ? -1 : 1);
    float s = 0.0f;
    for (int iy = -1; iy <= 1; ++iy)
        for (int ix = -1; ix <= 1; ++ix) {
            if (ix == ixm && iy == iym) continue;
            float xs = __builtin_fmaf(10.0f, (float)ix, a);
            float ys = __builtin_fmaf(10.0f, (float)iy, bb);
            s += RSQ(xs * xs + ys * ys);
        }
    float ux = 5.0f - __builtin_fabsf(__builtin_fabsf(a) - 5.0f);
    float uy = 5.0f - __builtin_fabsf(__builtin_fabsf(bb) - 5.0f);
    float r2 = __builtin_fmaf(uy, uy, ux * ux);
    float gcap = (r2 >= RC2) ? RSQ(r2)
                             : __builtin_fmaf(__builtin_fmaf(GC, r2, GB), r2, GA);
    return s + gcap;
}

// main: every block self-sufficient from xy (64 KB, L2-resident).
// [0,512): corr — own LDS histogram + own F rows + convolution.
// [512,912): sr — filter own 3x3 neighborhood into LDS, exact residual.
__global__ __launch_bounds__(128) void main_kernel(const float* __restrict__ xy,
                                                   float* __restrict__ corr_part,
                                                   float* __restrict__ sr_part) {
    const int t = threadIdx.x;
    const int b = blockIdx.x;
    __shared__ unsigned arena[5632];   // 22.5 KB, aliased per role
    __shared__ float wsum[2];
    const float4* __restrict__ xy4 = (const float4*)xy;   // 4096 quads = 8192 pts

    if (b < NCORR) {
        unsigned* lh = arena;                         // 4096 u32 histogram
        float (*rowF)[128] = (float (*)[128])(arena + 4096);   // 8x128
        float (*rowN)[64]  = (float (*)[64])(arena + 5120);    // 8x64

        for (int k = t; k < NBINS; k += 128) lh[k] = 0u;
        __syncthreads();
        for (int i = t; i < 4096; i += 128) {
            float4 v = xy4[i];
            int cx0 = (int)(v.x * BINV); cx0 = cx0 > 63 ? 63 : cx0;
            int cy0 = (int)(v.y * BINV); cy0 = cy0 > 63 ? 63 : cy0;
            atomicAdd(&lh[cy0 * BGRID + cx0], 1u);
            int cx1 = (int)(v.z * BINV); cx1 = cx1 > 63 ? 63 : cx1;
            int cy1 = (int)(v.w * BINV); cy1 = cy1 > 63 ? 63 : cy1;
            atomicAdd(&lh[cy1 * BGRID + cx1], 1u);
        }

        const int y1 = b >> 3;
        const int y2b = (b & 7) * 8;
#pragma unroll
        for (int s = 0; s < 8; ++s)
            if (t < FDIM)
                rowF[s][t] = Fnode((float)(t - 63) * FH, (float)(y1 - y2b - s) * FH);
        __syncthreads();

        for (int k = t; k < 512; k += 128)
            rowN[k >> 6][k & 63] = (float)lh[(y2b + (k >> 6)) * BGRID + (k & 63)];
        __syncthreads();

        const int x1 = t & 63;
        const int x2base = (t >> 6) * 32;
        const int fb = 63 + x1 - x2base;
        float n1 = (float)lh[y1 * BGRID + x1];
        float acc = 0.0f;
#pragma unroll
        for (int s = 0; s < 8; ++s) {
            const float* Fr = &rowF[s][0];
            const float* Nr = &rowN[s][x2base];
            float sum = 0.0f;
#pragma unroll 8
            for (int k = 0; k < 32; ++k)
                sum = __builtin_fmaf(Nr[k], Fr[fb - k], sum);   // Nr bcast, Fr stride-1
            acc += sum;
        }
        acc *= n1;
        for (int off = 32; off > 0; off >>= 1)
            acc += __shfl_down(acc, off, 64);
        if ((t & 63) == 0) wsum[t >> 6] = acc;
        __syncthreads();
        if (t == 0) corr_part[b] = wsum[0] + wsum[1];
        return;
    }

    // ---- short-range: filter own 3x3 neighborhood from the full point stream ----
    float* spx     = (float*)arena;            // 384
    float* spy     = (float*)(arena + 384);    // 384
    int*   stag    = (int*)(arena + 768);      // 384 (global point index)
    int*   sown    = (int*)(arena + 1152);     // 64 (indices into staged list)
    unsigned* cur  = arena + 1216;             // 2 cursors

    const int c  = b - NCORR;                  // 0..399
    const int cx = c % CELLG, cy = c / CELLG;
    if (t < 2) cur[t] = 0u;
    __syncthreads();

    for (int i = t; i < 4096; i += 128) {
        float4 v = xy4[i];
#pragma unroll
        for (int h = 0; h < 2; ++h) {
            float px = h ? v.z : v.x;
            float py = h ? v.w : v.y;
            int cx2 = (int)(px * CELLINV); cx2 = cx2 > CELLG - 1 ? CELLG - 1 : cx2;
            int cy2 = (int)(py * CELLINV); cy2 = cy2 > CELLG - 1 ? CELLG - 1 : cy2;
            int ddx = cx2 - cx;  ddx += (ddx < -CELLG/2) ? CELLG : 0;  ddx -= (ddx > CELLG/2) ? CELLG : 0;
            int ddy = cy2 - cy;  ddy += (ddy < -CELLG/2) ? CELLG : 0;  ddy -= (ddy > CELLG/2) ? CELLG : 0;
            if (ddx >= -1 && ddx <= 1 && ddy >= -1 && ddy <= 1) {
                unsigned m = atomicAdd(&cur[0], 1u);
                if (m < SRCAP) {
                    spx[m] = px;  spy[m] = py;  stag[m] = 2 * i + h;
                    if (ddx == 0 && ddy == 0) {
                        unsigned o = atomicAdd(&cur[1], 1u);
                        if (o < 64) sown[o] = (int)m;
                    }
                }
            }
        }
    }
    __syncthreads();
    int M  = (int)cur[0];  M  = M  > SRCAP ? SRCAP : M;
    int n0 = (int)cur[1];  n0 = n0 > 64 ? 64 : n0;

    float acc = 0.0f;
    for (int oi = 0; oi < n0; ++oi) {
        int i = sown[oi];                      // uniform -> LDS broadcast
        float pxi = spx[i], pyi = spy[i];
        int itag = stag[i];
        for (int j = t; j < M; j += 128) {     // stride-1 LDS
            float dx = pxi - spx[j];
            float dy = pyi - spy[j];
            float ux = 5.0f - __builtin_fabsf(__builtin_fabsf(dx) - 5.0f);
            float uy = 5.0f - __builtin_fabsf(__builtin_fabsf(dy) - 5.0f);
            float s2 = __builtin_fmaf(uy, uy, ux * ux);
            float v = RSQ(s2) - __builtin_fmaf(__builtin_fmaf(GC, s2, GB), s2, GA);
            bool ok = (s2 < RC2) && (stag[j] != itag);
            acc += ok ? v : 0.0f;
        }
    }
    for (int off = 32; off > 0; off >>= 1)
        acc += __shfl_down(acc, off, 64);
    if ((t & 63) == 0) wsum[t >> 6] = acc;
    __syncthreads();
    if (t == 0) sr_part[c] = wsum[0] + wsum[1];
}

// finish: corr + sr + KE - N*F(0,0) -> scalar.
__global__ __launch_bounds__(1024) void finish_kernel(const float* __restrict__ corr_part,
                                                      const float* __restrict__ sr_part,
                                                      const float* __restrict__ pxy,
                                                      float* __restrict__ out) {
    const int t = threadIdx.x;
    float acc = 0.0f;
    if (t < NCORR) acc += corr_part[t];
    if (t < NCELLS) acc += sr_part[t];
    const float4* p4 = (const float4*)pxy;     // KE = sum p^2 / 2 over 4096 quads
    for (int k = t; k < (2 * N) / 4; k += 1024) {
        float4 v = p4[k];
        acc += 0.5f * (v.x * v.x + v.y * v.y + v.z * v.z + v.w * v.w);
    }
    if (t == 0) acc -= (float)N * Fnode(0.0f, 0.0f);   // remove i==j bin pairs
    for (int off = 32; off > 0; off >>= 1)
        acc += __shfl_down(acc, off, 64);
    __shared__ float ws[16];
    if ((t & 63) == 0) ws[t >> 6] = acc;
    __syncthreads();
    if (t == 0) {
        float s = 0.0f;
        for (int w = 0; w < 16; ++w) s += ws[w];
        out[0] = s;
    }
}

extern "C" void kernel_launch(void* const* d_in, const int* in_sizes, int n_in,
                              void* d_out, int out_size, void* d_ws, size_t ws_size,
                              hipStream_t stream) {
    const float* xy  = (const float*)d_in[0];
    const float* pxy = (const float*)d_in[1];
    float* out       = (float*)d_out;
    float* wsf       = (float*)d_ws;
    float* corr_part = wsf + WS_CORR;
    float* sr_part   = wsf + WS_SR;

    main_kernel<<<NBLK, 128, 0, stream>>>(xy, corr_part, sr_part);
    finish_kernel<<<1, 1024, 0, stream>>>(corr_part, sr_part, pxy, out);
}

// Round 24
// 34.691 us; speedup vs baseline: 6.1950x; 1.0141x over previous
//
#include <hip/hip_runtime.h>

#define N 8192

// Smooth part: binned autocorrelation of F = H8 (8 non-min images) + g_cap(r_min).
#define BGRID 64
#define BINV 6.4f
#define FDIM 127
#define FH 0.15625f                // 10/64

// poly(s) = GA + GB*s + GC*s^2 (s = r^2), C1-matched to 1/r at rc=0.5.
#define RC2 0.25f
#define GA 3.75f
#define GB (-10.0f)
#define GC 12.0f

// Cell geometry for the short-range residual (r < 0.5 only).
#define CELLG 20
#define CELLINV 2.0f
#define NCELLS (CELLG * CELLG)     // 400
#define SRCAP 384                  // 3x3 neighborhood capacity (avg 185)

#define NCORR 256                  // (y1: 64) x (y2 quarter: 4), 16 y2-rows each
#define NROWS 16
#define NBLK (NCORR + NCELLS)      // 656

// ws layout (float-index offsets)
#define WS_CORR 0                  // 256 (pad 512)
#define WS_SR 512                  // 512

#define RSQ __builtin_amdgcn_rsqf

// F node: H8 (8 non-min images) + g_cap(min image) — same ops as the verified build.
__device__ __forceinline__ float Fnode(float a, float bb) {
    int ixm = (__builtin_fabsf(a)  <= 5.0f) ? 0 : (a  > 0.0f ? -1 : 1);
    int iym = (__builtin_fabsf(bb) <= 5.0f) ? 0 : (bb > 0.0f ? -1 : 1);
    float s = 0.0f;
    for (int iy = -1; iy <= 1; ++iy)
        for (int ix = -1; ix <= 1; ++ix) {
            if (ix == ixm && iy == iym) continue;
            float xs = __builtin_fmaf(10.0f, (float)ix, a);
            float ys = __builtin_fmaf(10.0f, (float)iy, bb);
            s += RSQ(xs * xs + ys * ys);
        }
    float ux = 5.0f - __builtin_fabsf(__builtin_fabsf(a) - 5.0f);
    float uy = 5.0f - __builtin_fabsf(__builtin_fabsf(bb) - 5.0f);
    float r2 = __builtin_fmaf(uy, uy, ux * ux);
    float gcap = (r2 >= RC2) ? RSQ(r2)
                             : __builtin_fmaf(__builtin_fmaf(GC, r2, GB), r2, GA);
    return s + gcap;
}

// main: every block self-sufficient from xy (64 KB, L2-resident).
// [0,256): corr — row-filtered LDS histogram (only the 17 rows this block needs).
// [256,656): sr — filter own 3x3 cell neighborhood into LDS, exact residual.
__global__ __launch_bounds__(128) void main_kernel(const float* __restrict__ xy,
                                                   float* __restrict__ corr_part,
                                                   float* __restrict__ sr_part) {
    const int t = threadIdx.x;
    const int b = blockIdx.x;
    __shared__ unsigned arena[4224];   // 16.9 KB, aliased per role
    __shared__ float wsum[2];
    const float4* __restrict__ xy4 = (const float4*)xy;   // 4096 quads = 8192 pts

    if (b < NCORR) {
        unsigned (*cnt)[64] = (unsigned (*)[64])arena;            // 17x64 u32
        float (*rowF)[128]  = (float (*)[128])(arena + 1088);     // 16x128 f32
        float (*rowNf)[64]  = (float (*)[64])(arena + 3136);      // 16x64 f32

        const int y1  = b >> 2;
        const int y2b = (b & 3) * NROWS;

        for (int k = t; k < 17 * 64; k += 128) ((unsigned*)cnt)[k] = 0u;
        __syncthreads();

        // stream all points; count only rows [y2b, y2b+16) and row y1
        for (int i = t; i < 4096; i += 128) {
            float4 v = xy4[i];
#pragma unroll
            for (int h = 0; h < 2; ++h) {
                float px = h ? v.z : v.x;
                float py = h ? v.w : v.y;
                int cx = (int)(px * BINV); cx = cx > 63 ? 63 : cx;
                int cy = (int)(py * BINV); cy = cy > 63 ? 63 : cy;
                int rel = cy - y2b;
                if (rel >= 0 && rel < NROWS) atomicAdd(&cnt[rel][cx], 1u);
                if (cy == y1)                atomicAdd(&cnt[NROWS][cx], 1u);
            }
        }

        // F rows for offsets (x: -63..63, y: y1 - (y2b+s))
#pragma unroll
        for (int s = 0; s < NROWS; ++s)
            if (t < FDIM)
                rowF[s][t] = Fnode((float)(t - 63) * FH, (float)(y1 - y2b - s) * FH);
        __syncthreads();

        for (int k = t; k < NROWS * 64; k += 128)
            rowNf[k >> 6][k & 63] = (float)cnt[k >> 6][k & 63];
        __syncthreads();

        const int x1 = t & 63;
        const int x2base = (t >> 6) * 32;
        const int fb = 63 + x1 - x2base;
        float n1 = (float)cnt[NROWS][x1];
        float acc = 0.0f;
#pragma unroll
        for (int s = 0; s < NROWS; ++s) {
            const float* Fr = &rowF[s][0];
            const float* Nr = &rowNf[s][x2base];
            float sum = 0.0f;
#pragma unroll 8
            for (int k = 0; k < 32; ++k)
                sum = __builtin_fmaf(Nr[k], Fr[fb - k], sum);   // Nr bcast, Fr stride-1
            acc += sum;
        }
        acc *= n1;
        for (int off = 32; off > 0; off >>= 1)
            acc += __shfl_down(acc, off, 64);
        if ((t & 63) == 0) wsum[t >> 6] = acc;
        __syncthreads();
        if (t == 0) corr_part[b] = wsum[0] + wsum[1];
        return;
    }

    // ---- short-range: filter own 3x3 neighborhood from the full point stream ----
    float* spx     = (float*)arena;            // 384
    float* spy     = (float*)(arena + 384);    // 384
    int*   stag    = (int*)(arena + 768);      // 384 (global point index)
    int*   sown    = (int*)(arena + 1152);     // 64 (indices into staged list)
    unsigned* cur  = arena + 1216;             // 2 cursors

    const int c  = b - NCORR;                  // 0..399
    const int cx = c % CELLG, cy = c / CELLG;
    if (t < 2) cur[t] = 0u;
    __syncthreads();

    for (int i = t; i < 4096; i += 128) {
        float4 v = xy4[i];
#pragma unroll
        for (int h = 0; h < 2; ++h) {
            float px = h ? v.z : v.x;
            float py = h ? v.w : v.y;
            int cx2 = (int)(px * CELLINV); cx2 = cx2 > CELLG - 1 ? CELLG - 1 : cx2;
            int cy2 = (int)(py * CELLINV); cy2 = cy2 > CELLG - 1 ? CELLG - 1 : cy2;
            int ddx = cx2 - cx;  ddx += (ddx < -CELLG/2) ? CELLG : 0;  ddx -= (ddx > CELLG/2) ? CELLG : 0;
            int ddy = cy2 - cy;  ddy += (ddy < -CELLG/2) ? CELLG : 0;  ddy -= (ddy > CELLG/2) ? CELLG : 0;
            if (ddx >= -1 && ddx <= 1 && ddy >= -1 && ddy <= 1) {
                unsigned m = atomicAdd(&cur[0], 1u);
                if (m < SRCAP) {
                    spx[m] = px;  spy[m] = py;  stag[m] = 2 * i + h;
                    if (ddx == 0 && ddy == 0) {
                        unsigned o = atomicAdd(&cur[1], 1u);
                        if (o < 64) sown[o] = (int)m;
                    }
                }
            }
        }
    }
    __syncthreads();
    int M  = (int)cur[0];  M  = M  > SRCAP ? SRCAP : M;
    int n0 = (int)cur[1];  n0 = n0 > 64 ? 64 : n0;

    float acc = 0.0f;
    for (int oi = 0; oi < n0; ++oi) {
        int i = sown[oi];                      // uniform -> LDS broadcast
        float pxi = spx[i], pyi = spy[i];
        int itag = stag[i];
        for (int j = t; j < M; j += 128) {     // stride-1 LDS
            float dx = pxi - spx[j];
            float dy = pyi - spy[j];
            float ux = 5.0f - __builtin_fabsf(__builtin_fabsf(dx) - 5.0f);
            float uy = 5.0f - __builtin_fabsf(__builtin_fabsf(dy) - 5.0f);
            float s2 = __builtin_fmaf(uy, uy, ux * ux);
            float v = RSQ(s2) - __builtin_fmaf(__builtin_fmaf(GC, s2, GB), s2, GA);
            bool ok = (s2 < RC2) && (stag[j] != itag);
            acc += ok ? v : 0.0f;
        }
    }
    for (int off = 32; off > 0; off >>= 1)
        acc += __shfl_down(acc, off, 64);
    if ((t & 63) == 0) wsum[t >> 6] = acc;
    __syncthreads();
    if (t == 0) sr_part[c] = wsum[0] + wsum[1];
}

// finish: corr + sr + KE - N*F(0,0) -> scalar.
__global__ __launch_bounds__(1024) void finish_kernel(const float* __restrict__ corr_part,
                                                      const float* __restrict__ sr_part,
                                                      const float* __restrict__ pxy,
                                                      float* __restrict__ out) {
    const int t = threadIdx.x;
    float acc = 0.0f;
    if (t < NCORR) acc += corr_part[t];
    if (t < NCELLS) acc += sr_part[t];
    const float4* p4 = (const float4*)pxy;     // KE = sum p^2 / 2 over 4096 quads
    for (int k = t; k < (2 * N) / 4; k += 1024) {
        float4 v = p4[k];
        acc += 0.5f * (v.x * v.x + v.y * v.y + v.z * v.z + v.w * v.w);
    }
    if (t == 0) acc -= (float)N * Fnode(0.0f, 0.0f);   // remove i==j bin pairs
    for (int off = 32; off > 0; off >>= 1)
        acc += __shfl_down(acc, off, 64);
    __shared__ float ws[16];
    if ((t & 63) == 0) ws[t >> 6] = acc;
    __syncthreads();
    if (t == 0) {
        float s = 0.0f;
        for (int w = 0; w < 16; ++w) s += ws[w];
        out[0] = s;
    }
}

extern "C" void kernel_launch(void* const* d_in, const int* in_sizes, int n_in,
                              void* d_out, int out_size, void* d_ws, size_t ws_size,
                              hipStream_t stream) {
    const float* xy  = (const float*)d_in[0];
    const float* pxy = (const float*)d_in[1];
    float* out       = (float*)d_out;
    float* wsf       = (float*)d_ws;
    float* corr_part = wsf + WS_CORR;
    float* sr_part   = wsf + WS_SR;

    main_kernel<<<NBLK, 128, 0, stream>>>(xy, corr_part, sr_part);
    finish_kernel<<<1, 1024, 0, stream>>>(corr_part, sr_part, pxy, out);
}